// Round 1
// baseline (548.824 us; speedup 1.0000x reference)
//
#include <hip/hip_runtime.h>

// Problem sizes: N=64, C=64, T=300, V=25, S=3, inter=16
typedef __bf16 bf16;
typedef bf16 bf16x8 __attribute__((ext_vector_type(8)));
typedef bf16 bf16x4 __attribute__((ext_vector_type(4)));
typedef float f32x4 __attribute__((ext_vector_type(4)));

// ---- workspace byte offsets (total ~15.0 MB) ----
#define WS_WAB   0u          // bf16 [3][32][64]   rows 0-15=Wa, 16-31=Wb
#define WS_WD    12288u      // bf16 [3][64][64]
#define WS_COEFA 36864u      // f32  [64]  bn scale
#define WS_COEFB 37120u      // f32  [64]  bn bias (incl. bd-sum)
#define WS_GT    37376u      // bf16 [64][3][32][32]  G transposed: GT[w][v]=G[v][w], zero-padded
#define WS_MPART 430592u     // f32  [64][8][3][32][32] M partials per t-segment
#define WS_STP   6722048u    // f32  [64][8][64][25]  sum-over-t(y) partials per segment
#define WS_SE1   9998848u    // f32  [64][32]   1+se1[v]
#define WS_SVP   10007040u   // f32  [64][64][300]  sum_v y*(1+se1)
#define WS_SE2   14922240u   // f32  [64][300]  1+se2[t]
#define WS_SE3   14999040u   // f32  [64][64]   1+se3[c]

__device__ __forceinline__ f32x4 mfma16(bf16x8 a, bf16x8 b, f32x4 c) {
  return __builtin_amdgcn_mfma_f32_16x16x32_bf16(a, b, c, 0, 0, 0);
}

// ---------------- P0: weight prep ----------------
__global__ __launch_bounds__(256) void k_prep(
    const float* __restrict__ Wa, const float* __restrict__ Wb,
    const float* __restrict__ Wd, const float* __restrict__ bd,
    const float* __restrict__ gam, const float* __restrict__ bet,
    const float* __restrict__ mean, const float* __restrict__ var,
    char* __restrict__ ws) {
  bf16* wab = (bf16*)(ws + WS_WAB);
  bf16* wd  = (bf16*)(ws + WS_WD);
  float* cA = (float*)(ws + WS_COEFA);
  float* cB = (float*)(ws + WS_COEFB);
  int tid = threadIdx.x;
  for (int f = tid; f < 3*32*64; f += 256) {
    int s = f >> 11, r = (f >> 6) & 31, c = f & 63;
    float v = (r < 16) ? Wa[(s*16 + r)*64 + c] : Wb[(s*16 + (r-16))*64 + c];
    wab[f] = (bf16)v;
  }
  for (int f = tid; f < 3*64*64; f += 256) wd[f] = (bf16)Wd[f];
  if (tid < 64) {
    float bds = bd[tid] + bd[64+tid] + bd[128+tid];
    float iv = gam[tid] / sqrtf(var[tid] + 1e-5f);
    cA[tid] = iv;
    cB[tid] = (bds - mean[tid]) * iv + bet[tid];
  }
}

// ---------------- K1: fused a,b projection + M partial accumulation ----------------
// grid (8 segs, 64 n), 256 thr. Per chunk of 2 t's:
//  stage1 (MFMA): ab[i, (t,v)] = Wab . X   (rows=(s,ab,i) 6 tiles, cols=(tt,v) 4 tiles, K=64)
//  stage2 (MFMA): M[v,w] += a^T b          (K = 2tt x 16i = 32)
__global__ __launch_bounds__(256) void k1_m(
    const float* __restrict__ x, const float* __restrict__ ba,
    const float* __restrict__ bb, char* __restrict__ ws) {
  __shared__ __attribute__((aligned(16))) bf16 XT[2*32*72];       // [tt][v(pad32)][c(pad72)] = x[c][t][v]
  __shared__ __attribute__((aligned(16))) bf16 AB[3*2*32*3*24];   // [s][ab][vw32][ttpad3][ipad24]
  __shared__ __attribute__((aligned(16))) bf16 WL[3*32*72];       // [s][row32][c(pad72)]
  const int seg = blockIdx.x, n = blockIdx.y;
  const int tid = threadIdx.x;
  const int lane = tid & 63, wv = tid >> 6;
  const int l15 = lane & 15, l4 = lane >> 4;
  const int t0 = seg*38, tlen = min(38, 300 - t0);
  const bf16* wab = (const bf16*)(ws + WS_WAB);

  for (int f = tid; f < 3*32*64; f += 256) {
    int s = f >> 11, r = (f >> 6) & 31, c = f & 63;
    WL[(s*32 + r)*72 + c] = wab[f];
  }
  // zero v-pad rows of XT once (rows 25..31 per tt); pad stays zero forever
  for (int f = tid; f < 2*7*72; f += 256) {
    int tt = f / 504, rem = f % 504;
    XT[(tt*32 + 25 + rem/72)*72 + (rem % 72)] = (bf16)0.f;
  }
  const f32x4 z4 = {0.f,0.f,0.f,0.f};
  f32x4 macc[3]; macc[0]=z4; macc[1]=z4; macc[2]=z4;
  const int vt = wv >> 1, wt = wv & 1;  // stage2 output tile of this wave
  __syncthreads();

  for (int ch = 0; ch < 19; ++ch) {
    if (ch*2 >= tlen) break;
    // fill XT (transpose x[c][t][v] -> [tt][v][c], bf16)
    for (int f = tid; f < 64*50; f += 256) {
      int c = f / 50, rem = f % 50, tt = rem / 25, v = rem % 25;
      int tl = ch*2 + tt;
      float val = (tl < tlen) ? x[((n*64 + c)*300 + (t0 + tl))*25 + v] : 0.f;
      XT[(tt*32 + v)*72 + c] = (bf16)val;
    }
    __syncthreads();
    // stage1: wave -> coltile ct=wv (tt=ct>>1, vhalf=ct&1)
    {
      const int ct = wv, tt = ct >> 1, vbase = (ct & 1) * 16;
      f32x4 acc[6];
      #pragma unroll
      for (int rt = 0; rt < 6; ++rt) acc[rt] = z4;
      #pragma unroll
      for (int kk = 0; kk < 2; ++kk) {
        bf16x8 B = *(const bf16x8*)&XT[(tt*32 + vbase + l15)*72 + kk*32 + 8*l4];
        #pragma unroll
        for (int rt = 0; rt < 6; ++rt) {
          bf16x8 A = *(const bf16x8*)&WL[((rt>>1)*32 + (rt&1)*16 + l15)*72 + kk*32 + 8*l4];
          acc[rt] = mfma16(A, B, acc[rt]);
        }
      }
      const int tl = ch*2 + tt;
      const bool tv = (tl < tlen);
      const int vcol = vbase + l15;
      const int i0 = 4*l4;
      #pragma unroll
      for (int rt = 0; rt < 6; ++rt) {
        const int s = rt >> 1, ab = rt & 1;
        bf16x4 pk;
        #pragma unroll
        for (int r = 0; r < 4; ++r) {
          float bias = (ab ? bb : ba)[s*16 + i0 + r];
          pk[r] = (bf16)(tv ? (acc[rt][r] + bias) : 0.f);
        }
        *(bf16x4*)&AB[(((s*2 + ab)*32 + vcol)*3 + tt)*24 + i0] = pk;
      }
    }
    __syncthreads();
    // stage2: M[v,w] += a^T b over K=32 (tt = l4>>1, i0 = 8*(l4&1))
    {
      const int tt = l4 >> 1, i0 = 8*(l4 & 1);
      #pragma unroll
      for (int s = 0; s < 3; ++s) {
        bf16x8 A = *(const bf16x8*)&AB[(((s*2 + 0)*32 + vt*16 + l15)*3 + tt)*24 + i0];
        bf16x8 B = *(const bf16x8*)&AB[(((s*2 + 1)*32 + wt*16 + l15)*3 + tt)*24 + i0];
        macc[s] = mfma16(A, B, macc[s]);
      }
    }
    __syncthreads();
  }
  float* mp = (float*)(ws + WS_MPART);
  #pragma unroll
  for (int s = 0; s < 3; ++s) {
    #pragma unroll
    for (int r = 0; r < 4; ++r) {
      int v = vt*16 + 4*l4 + r, w = wt*16 + l15;
      mp[(((n*8 + seg)*3 + s)*32 + v)*32 + w] = macc[s][r];
    }
  }
}

// ---------------- K1b: reduce M partials -> GT (bf16, transposed, zero-padded) ----------------
__global__ __launch_bounds__(256) void k1b_g(
    const float* __restrict__ A, const float* __restrict__ alp,
    char* __restrict__ ws) {
  int e = blockIdx.x*256 + threadIdx.x;   // 196608 exact
  int w = e & 31, v = (e >> 5) & 31;
  int s = (e >> 10) % 3, n = e / 3072;
  const float* mp = (const float*)(ws + WS_MPART);
  float m = 0.f;
  #pragma unroll
  for (int p = 0; p < 8; ++p)
    m += mp[(((n*8 + p)*3 + s)*32 + v)*32 + w];
  float g = 0.f;
  if (v < 25 && w < 25)
    g = A[(s*25 + v)*25 + w] + alp[0] * tanhf(m * (1.f/4800.f));
  bf16* gt = (bf16*)(ws + WS_GT);
  gt[((n*3 + s)*32 + w)*32 + v] = (bf16)g;   // transposed write
}

// ---------------- K3: fused graph conv + BN + residual + ReLU + sumT partials ----------------
// grid (8 segs, 64 n), 512 thr (8 waves). Per tt: u[s,o,v]=Wd.X (MFMA), y=sum_s u.G (MFMA), epilogue.
__global__ __launch_bounds__(512) void k3_y(
    const float* __restrict__ x, char* __restrict__ ws,
    float* __restrict__ out) {
  __shared__ __attribute__((aligned(16))) bf16 XT[4*32*72];   // [tt][v(pad32)][c(pad72)]
  __shared__ __attribute__((aligned(16))) bf16 UL[3*64*40];   // [s][o][v(pad40)]
  __shared__ __attribute__((aligned(16))) bf16 GL[3*32*40];   // [s][w][v(pad40)] = G[v][w]
  const int seg = blockIdx.x, n = blockIdx.y;
  const int tid = threadIdx.x;
  const int lane = tid & 63, wv = tid >> 6;
  const int l15 = lane & 15, l4 = lane >> 4;
  const int t0 = seg*38, tlen = min(38, 300 - t0);
  const bf16* gt = (const bf16*)(ws + WS_GT);
  const bf16* wd = (const bf16*)(ws + WS_WD);
  const float* cA = (const float*)(ws + WS_COEFA);
  const float* cB = (const float*)(ws + WS_COEFB);

  for (int f = tid; f < 3*32*32; f += 512) {
    int s = f >> 10, w = (f >> 5) & 31, v = f & 31;
    GL[(s*32 + w)*40 + v] = gt[n*3072 + f];
  }
  for (int f = tid; f < 4*7*72; f += 512) {
    int tt = f / 504, rem = f % 504;
    XT[(tt*32 + 25 + rem/72)*72 + (rem % 72)] = (bf16)0.f;
  }
  const int ot2 = wv >> 1, wt2 = wv & 1;   // stage2/epilogue tile
  const int o0 = ot2*16 + 4*l4;
  const int wo = wt2*16 + l15;
  float cAr[4], cBr[4];
  #pragma unroll
  for (int r = 0; r < 4; ++r) { cAr[r] = cA[o0 + r]; cBr[r] = cB[o0 + r]; }
  float st[4] = {0.f, 0.f, 0.f, 0.f};
  const f32x4 z4 = {0.f,0.f,0.f,0.f};
  __syncthreads();

  for (int ch = 0; ch < 10; ++ch) {
    if (ch*4 >= tlen) break;
    for (int f = tid; f < 64*100; f += 512) {
      int c = f / 100, rem = f % 100, tt = rem / 25, v = rem % 25;
      int tl = ch*4 + tt;
      float val = (tl < tlen) ? x[((n*64 + c)*300 + (t0 + tl))*25 + v] : 0.f;
      XT[(tt*32 + v)*72 + c] = (bf16)val;
    }
    __syncthreads();
    for (int tt = 0; tt < 4; ++tt) {
      // stage1: u[s][o][v] = sum_c Wd[s][o][c] * x[c][t][v]
      {
        const int ot1 = wv >> 1, vt1 = wv & 1;
        f32x4 acc[3]; acc[0]=z4; acc[1]=z4; acc[2]=z4;
        #pragma unroll
        for (int kk = 0; kk < 2; ++kk) {
          bf16x8 B = *(const bf16x8*)&XT[(tt*32 + vt1*16 + l15)*72 + kk*32 + 8*l4];
          #pragma unroll
          for (int s = 0; s < 3; ++s) {
            bf16x8 Af = *(const bf16x8*)&wd[(s*64 + ot1*16 + l15)*64 + kk*32 + 8*l4];
            acc[s] = mfma16(Af, B, acc[s]);
          }
        }
        const int vcol = vt1*16 + l15;
        const int ob = ot1*16 + 4*l4;
        #pragma unroll
        for (int s = 0; s < 3; ++s) {
          #pragma unroll
          for (int r = 0; r < 4; ++r)
            UL[(s*64 + ob + r)*40 + vcol] = (bf16)acc[s][r];
        }
      }
      __syncthreads();
      // stage2: y[o][w] = sum_s sum_v u[s][o][v] * G[v][w]; epilogue
      {
        f32x4 acc = z4;
        #pragma unroll
        for (int s = 0; s < 3; ++s) {
          bf16x8 Af = *(const bf16x8*)&UL[(s*64 + ot2*16 + l15)*40 + 8*l4];
          bf16x8 Bf = *(const bf16x8*)&GL[(s*32 + wt2*16 + l15)*40 + 8*l4];
          acc = mfma16(Af, Bf, acc);
        }
        const int tl = ch*4 + tt;
        if (tl < tlen && wo < 25) {
          const int t = t0 + tl;
          #pragma unroll
          for (int r = 0; r < 4; ++r) {
            const int idx = ((n*64 + o0 + r)*300 + t)*25 + wo;
            float val = acc[r]*cAr[r] + cBr[r] + x[idx];
            val = fmaxf(val, 0.f);
            out[idx] = val;
            st[r] += val;
          }
        }
      }
      __syncthreads();
    }
  }
  float* stp = (float*)(ws + WS_STP);
  if (wo < 25) {
    #pragma unroll
    for (int r = 0; r < 4; ++r)
      stp[((n*8 + seg)*64 + o0 + r)*25 + wo] = st[r];
  }
}

// ---------------- K4: se1 (spatial attention weights) ----------------
__global__ __launch_bounds__(256) void k4_se1(
    const float* __restrict__ Wsa, const float* __restrict__ bsa,
    char* __restrict__ ws) {
  __shared__ float Sm[64][26];
  __shared__ float red[25][8];
  int n = blockIdx.x, tid = threadIdx.x;
  const float* stp = (const float*)(ws + WS_STP);
  for (int f = tid; f < 1600; f += 256) {
    int c = f / 25, v = f % 25;
    float s = 0.f;
    #pragma unroll
    for (int p = 0; p < 8; ++p) s += stp[((n*8 + p)*64 + c)*25 + v];
    Sm[c][v] = s * (1.f/300.f);
  }
  __syncthreads();
  float acc = 0.f;
  int v = tid >> 3, part = tid & 7;
  if (tid < 200) {
    for (int c = part; c < 64; c += 8) {
      #pragma unroll
      for (int k = 0; k < 25; ++k) {
        int vv = v + k - 12;
        if (vv >= 0 && vv < 25) acc += Wsa[c*25 + k] * Sm[c][vv];
      }
    }
    red[v][part] = acc;
  }
  __syncthreads();
  if (tid < 25) {
    float a = bsa[0];
    #pragma unroll
    for (int p = 0; p < 8; ++p) a += red[tid][p];
    ((float*)(ws + WS_SE1))[n*32 + tid] = 1.f + 1.f/(1.f + expf(-a));
  }
}

// ---------------- K5: weighted sum over V ----------------
__global__ __launch_bounds__(256) void k5_sv(
    const float* __restrict__ y, char* __restrict__ ws) {
  __shared__ float w1[25];
  int c = blockIdx.x, n = blockIdx.y, tid = threadIdx.x;
  if (tid < 25) w1[tid] = ((const float*)(ws + WS_SE1))[n*32 + tid];
  __syncthreads();
  float* svp = (float*)(ws + WS_SVP);
  for (int t = tid; t < 300; t += 256) {
    const float* row = y + ((size_t)(n*64 + c)*300 + t)*25;
    float acc = 0.f;
    #pragma unroll
    for (int v = 0; v < 25; ++v) acc += row[v] * w1[v];
    svp[(n*64 + c)*300 + t] = acc;
  }
}

// ---------------- K6a: se2 (temporal attention weights) ----------------
__global__ __launch_bounds__(320) void k6a_se2(
    const float* __restrict__ Wta, const float* __restrict__ bta,
    char* __restrict__ ws) {
  __shared__ float WLa[576];
  int n = blockIdx.x, tid = threadIdx.x;
  for (int f = tid; f < 576; f += 320) WLa[f] = Wta[f];
  __syncthreads();
  const float* svp = (const float*)(ws + WS_SVP);
  if (tid < 300) {
    float acc = 0.f;
    for (int c = 0; c < 64; ++c) {
      const float* rowp = svp + (n*64 + c)*300;
      #pragma unroll
      for (int k = 0; k < 9; ++k) {
        int t2 = tid + k - 4;
        if (t2 >= 0 && t2 < 300) acc += WLa[c*9 + k] * rowp[t2];
      }
    }
    float a = acc * (1.f/25.f) + bta[0];
    ((float*)(ws + WS_SE2))[n*300 + tid] = 1.f + 1.f/(1.f + expf(-a));
  }
}

// ---------------- K6b: se3 (channel attention, squeeze-excite) ----------------
__global__ __launch_bounds__(256) void k6b_se3(
    const float* __restrict__ Wfc1, const float* __restrict__ bfc1,
    const float* __restrict__ Wfc2, const float* __restrict__ bfc2,
    char* __restrict__ ws) {
  __shared__ float stv[64][4];
  __shared__ float m[64];
  __shared__ float h[32];
  int n = blockIdx.x, tid = threadIdx.x;
  const float* svp = (const float*)(ws + WS_SVP);
  const float* w2 = (const float*)(ws + WS_SE2) + n*300;
  {
    int c = tid & 63, p = tid >> 6;
    float acc = 0.f;
    for (int t = p*75; t < p*75 + 75; ++t)
      acc += w2[t] * svp[(n*64 + c)*300 + t];
    stv[c][p] = acc;
  }
  __syncthreads();
  if (tid < 64) m[tid] = (stv[tid][0]+stv[tid][1]+stv[tid][2]+stv[tid][3]) * (1.f/7500.f);
  __syncthreads();
  if (tid < 32) {
    float a = bfc1[tid];
    for (int c = 0; c < 64; ++c) a += Wfc1[tid*64 + c] * m[c];
    h[tid] = fmaxf(a, 0.f);
  }
  __syncthreads();
  if (tid < 64) {
    float a = bfc2[tid];
    #pragma unroll
    for (int j = 0; j < 32; ++j) a += Wfc2[tid*32 + j] * h[j];
    ((float*)(ws + WS_SE3))[n*64 + tid] = 1.f + 1.f/(1.f + expf(-a));
  }
}

// ---------------- K7: final elementwise scale (in-place on d_out) ----------------
__global__ __launch_bounds__(256) void k7_scale(
    float* __restrict__ out, const char* __restrict__ ws) {
  int g = blockIdx.x*256 + threadIdx.x;
  long e0 = (long)g * 4;
  if (e0 >= 30720000L) return;
  const float* w1 = (const float*)(ws + WS_SE1);
  const float* w2 = (const float*)(ws + WS_SE2);
  const float* w3 = (const float*)(ws + WS_SE3);
  float4 val = *(const float4*)(out + e0);
  float r[4] = {val.x, val.y, val.z, val.w};
  #pragma unroll
  for (int j = 0; j < 4; ++j) {
    long e = e0 + j;
    int v = (int)(e % 25);
    long q = e / 25;
    int t = (int)(q % 300);
    long q2 = q / 300;
    int c = (int)(q2 & 63);
    int n = (int)(q2 >> 6);
    r[j] *= w1[n*32 + v] * w2[n*300 + t] * w3[n*64 + c];
  }
  float4 ov = {r[0], r[1], r[2], r[3]};
  *(float4*)(out + e0) = ov;
}

extern "C" void kernel_launch(void* const* d_in, const int* in_sizes, int n_in,
                              void* d_out, int out_size, void* d_ws, size_t ws_size,
                              hipStream_t stream) {
  const float* x    = (const float*)d_in[0];
  const float* A    = (const float*)d_in[1];
  const float* alp  = (const float*)d_in[2];
  const float* Wa   = (const float*)d_in[3];
  const float* ba   = (const float*)d_in[4];
  const float* Wb   = (const float*)d_in[5];
  const float* bb   = (const float*)d_in[6];
  const float* Wd   = (const float*)d_in[7];
  const float* bd   = (const float*)d_in[8];
  const float* gam  = (const float*)d_in[9];
  const float* bet  = (const float*)d_in[10];
  const float* mean = (const float*)d_in[11];
  const float* var  = (const float*)d_in[12];
  const float* Wsa  = (const float*)d_in[13];
  const float* bsa  = (const float*)d_in[14];
  const float* Wta  = (const float*)d_in[15];
  const float* bta  = (const float*)d_in[16];
  const float* Wfc1 = (const float*)d_in[17];
  const float* bfc1 = (const float*)d_in[18];
  const float* Wfc2 = (const float*)d_in[19];
  const float* bfc2 = (const float*)d_in[20];
  char* ws = (char*)d_ws;
  float* out = (float*)d_out;

  k_prep<<<dim3(1), dim3(256), 0, stream>>>(Wa, Wb, Wd, bd, gam, bet, mean, var, ws);
  k1_m<<<dim3(8, 64), dim3(256), 0, stream>>>(x, ba, bb, ws);
  k1b_g<<<dim3(768), dim3(256), 0, stream>>>(A, alp, ws);
  k3_y<<<dim3(8, 64), dim3(512), 0, stream>>>(x, ws, out);
  k4_se1<<<dim3(64), dim3(256), 0, stream>>>(Wsa, bsa, ws);
  k5_sv<<<dim3(64, 64), dim3(256), 0, stream>>>(out, ws);
  k6a_se2<<<dim3(64), dim3(320), 0, stream>>>(Wta, bta, ws);
  k6b_se3<<<dim3(64), dim3(256), 0, stream>>>(Wfc1, bfc1, Wfc2, bfc2, ws);
  k7_scale<<<dim3(30000), dim3(256), 0, stream>>>(out, ws);
}

// Round 2
// 338.651 us; speedup vs baseline: 1.6206x; 1.6206x over previous
//
#include <hip/hip_runtime.h>

// Problem sizes: N=64, C=64, T=300, V=25, S=3, inter=16
typedef __bf16 bf16;
typedef bf16 bf16x8 __attribute__((ext_vector_type(8)));
typedef bf16 bf16x4 __attribute__((ext_vector_type(4)));
typedef float f32x4 __attribute__((ext_vector_type(4)));

// ---- workspace byte offsets (total ~76.5 MB) ----
#define WS_XG    0u           // bf16 [64][300][25][64]  x transposed: XG[n][t][v][c], +16KB tail pad
#define WS_WAB   61456384u    // bf16 [3][32][64]   rows 0-15=Wa, 16-31=Wb
#define WS_WD    61468672u    // bf16 [3][64][64]
#define WS_COEFA 61493248u    // f32  [64]  bn scale
#define WS_COEFB 61493504u    // f32  [64]  bn bias (incl. bd-sum)
#define WS_GT    61493760u    // bf16 [64][3][32][32]  GT[w][v]=G[v][w], zero-padded
#define WS_MPART 61886976u    // f32  [64][8][3][32][32] M partials per t-segment
#define WS_STP   68178432u    // f32  [64][8][64][25]  sum-over-t(y) partials per segment
#define WS_SE1   71455232u    // f32  [64][32]   1+se1[v]
#define WS_SVP   71463424u    // f32  [64][64][300]  sum_v y*(1+se1)
#define WS_SE2   76378624u    // f32  [64][300]  1+se2[t]
#define WS_SE3   76455424u    // f32  [64][64]   1+se3[c]

__device__ __forceinline__ f32x4 mfma16(bf16x8 a, bf16x8 b, f32x4 c) {
  return __builtin_amdgcn_mfma_f32_16x16x32_bf16(a, b, c, 0, 0, 0);
}

// ---------------- P0: weight prep ----------------
__global__ __launch_bounds__(256) void k_prep(
    const float* __restrict__ Wa, const float* __restrict__ Wb,
    const float* __restrict__ Wd, const float* __restrict__ bd,
    const float* __restrict__ gam, const float* __restrict__ bet,
    const float* __restrict__ mean, const float* __restrict__ var,
    char* __restrict__ ws) {
  bf16* wab = (bf16*)(ws + WS_WAB);
  bf16* wd  = (bf16*)(ws + WS_WD);
  float* cA = (float*)(ws + WS_COEFA);
  float* cB = (float*)(ws + WS_COEFB);
  int tid = threadIdx.x;
  for (int f = tid; f < 3*32*64; f += 256) {
    int s = f >> 11, r = (f >> 6) & 31, c = f & 63;
    float v = (r < 16) ? Wa[(s*16 + r)*64 + c] : Wb[(s*16 + (r-16))*64 + c];
    wab[f] = (bf16)v;
  }
  for (int f = tid; f < 3*64*64; f += 256) wd[f] = (bf16)Wd[f];
  if (tid < 64) {
    float bds = bd[tid] + bd[64+tid] + bd[128+tid];
    float iv = gam[tid] / sqrtf(var[tid] + 1e-5f);
    cA[tid] = iv;
    cB[tid] = (bds - mean[tid]) * iv + bet[tid];
  }
}

// ---------------- k_tr: transpose x[n][c][t][v] f32 -> XG[n][t][v][c] bf16 ----------------
__global__ __launch_bounds__(256) void k_tr(
    const float* __restrict__ x, char* __restrict__ ws) {
  __shared__ __attribute__((aligned(16))) bf16 tile[64*410];  // [c][flat tv 400, pad 410]
  const int tc = blockIdx.x, n = blockIdx.y, tid = threadIdx.x;
  const int t0 = tc*16;
  const int vmax = min(400, 7500 - t0*25);   // 400, or 300 for last chunk
  bf16* XG = (bf16*)(ws + WS_XG);
  // phase A: coalesced float4 reads of x rows, bf16 into LDS
  for (int u = tid; u < 6400; u += 256) {
    int c = u / 100, q = u % 100;
    int idx = 4*q;
    if (idx < vmax) {
      float4 val = *(const float4*)(x + (size_t)(n*64 + c)*7500 + t0*25 + idx);
      bf16* p = &tile[c*410 + idx];
      p[0] = (bf16)val.x; p[1] = (bf16)val.y; p[2] = (bf16)val.z; p[3] = (bf16)val.w;
    }
  }
  __syncthreads();
  // phase B: gather c-contiguous rows, 16B coalesced stores
  for (int k = 0; k < 16; ++k) {
    int u = tid + k*256;
    int c8 = u & 7, v = (u >> 3) & 31, dt = u >> 8;  // dt == k for tid<256
    int t = t0 + dt;
    if (v < 25 && t < 300) {
      bf16x8 pk;
      #pragma unroll
      for (int j = 0; j < 8; ++j) pk[j] = tile[(c8*8 + j)*410 + dt*25 + v];
      *(bf16x8*)&XG[((size_t)(n*300 + t)*25 + v)*64 + c8*8] = pk;
    }
  }
}

// ---------------- K1: fused a,b projection + M partial accumulation ----------------
// grid (8 seg, 64 n), 256 thr (4 waves). Chunk = 4 t, wave owns one t for stage1.
// stage1: ab[i,(v)] = Wab . x_t  (B-frags direct from XG), write AB[sab][v][k=tt*16+i]
// stage2: M[v,w] += a^T b  (K=64 over (tt,i)), 2 barriers per 4 t.
__global__ __launch_bounds__(256) void k1_m(
    const float* __restrict__ ba_g, const float* __restrict__ bb_g,
    char* __restrict__ ws) {
  __shared__ __attribute__((aligned(16))) bf16 AB[6*32*72];   // [s*2+ab][v32][k64 pad72]
  const int seg = blockIdx.x, n = blockIdx.y;
  const int tid = threadIdx.x;
  const int lane = tid & 63, wv = tid >> 6;
  const int l15 = lane & 15, l4 = lane >> 4;
  const int t0 = seg*38, tlen = min(38, 300 - t0);
  const bf16* XG  = (const bf16*)(ws + WS_XG);
  const bf16* wab = (const bf16*)(ws + WS_WAB);
  const f32x4 z4 = {0.f,0.f,0.f,0.f};

  // hoist A-frags (Wab rows) + biases
  bf16x8 Afr[6][2];
  float bias[6][4];
  #pragma unroll
  for (int rt = 0; rt < 6; ++rt) {
    const int s = rt >> 1, abk = rt & 1;
    #pragma unroll
    for (int kk = 0; kk < 2; ++kk)
      Afr[rt][kk] = *(const bf16x8*)&wab[(s*32 + abk*16 + l15)*64 + kk*32 + 8*l4];
    const float* bp = abk ? bb_g : ba_g;
    #pragma unroll
    for (int r = 0; r < 4; ++r) bias[rt][r] = bp[s*16 + 4*l4 + r];
  }
  f32x4 macc[3]; macc[0]=z4; macc[1]=z4; macc[2]=z4;
  const int vt2 = wv >> 1, wt2 = wv & 1;
  const int nch = (tlen + 3) >> 2;

  for (int ch = 0; ch < nch; ++ch) {
    const int tl = ch*4 + wv;
    const int t = t0 + tl;            // may read past 300 into ws pad (discarded)
    const bool tv = (tl < tlen);
    // stage1: this wave's t
    #pragma unroll
    for (int vt = 0; vt < 2; ++vt) {
      f32x4 acc[6];
      #pragma unroll
      for (int rt = 0; rt < 6; ++rt) acc[rt] = z4;
      #pragma unroll
      for (int kk = 0; kk < 2; ++kk) {
        bf16x8 B = *(const bf16x8*)&XG[((size_t)(n*300 + t)*25 + vt*16 + l15)*64 + kk*32 + 8*l4];
        #pragma unroll
        for (int rt = 0; rt < 6; ++rt) acc[rt] = mfma16(Afr[rt][kk], B, acc[rt]);
      }
      #pragma unroll
      for (int rt = 0; rt < 6; ++rt) {
        bf16x4 pk;
        #pragma unroll
        for (int r = 0; r < 4; ++r)
          pk[r] = (bf16)(tv ? (acc[rt][r] + bias[rt][r]) : 0.f);
        *(bf16x4*)&AB[(rt*32 + vt*16 + l15)*72 + wv*16 + 4*l4] = pk;
      }
    }
    __syncthreads();
    // stage2: M tile (vt2, wt2), K = 64 (4t x 16i)
    #pragma unroll
    for (int s = 0; s < 3; ++s) {
      #pragma unroll
      for (int kk = 0; kk < 2; ++kk) {
        bf16x8 Aa = *(const bf16x8*)&AB[((s*2 + 0)*32 + vt2*16 + l15)*72 + kk*32 + 8*l4];
        bf16x8 Bb = *(const bf16x8*)&AB[((s*2 + 1)*32 + wt2*16 + l15)*72 + kk*32 + 8*l4];
        macc[s] = mfma16(Aa, Bb, macc[s]);
      }
    }
    __syncthreads();
  }
  float* mp = (float*)(ws + WS_MPART);
  #pragma unroll
  for (int s = 0; s < 3; ++s) {
    #pragma unroll
    for (int r = 0; r < 4; ++r) {
      int v = vt2*16 + 4*l4 + r, w = wt2*16 + l15;
      mp[(((n*8 + seg)*3 + s)*32 + v)*32 + w] = macc[s][r];
    }
  }
}

// ---------------- K1b: reduce M partials -> GT (bf16, transposed, zero-padded) ----------------
__global__ __launch_bounds__(256) void k1b_g(
    const float* __restrict__ A, const float* __restrict__ alp,
    char* __restrict__ ws) {
  int e = blockIdx.x*256 + threadIdx.x;   // 196608 exact
  int w = e & 31, v = (e >> 5) & 31;
  int s = (e >> 10) % 3, n = e / 3072;
  const float* mp = (const float*)(ws + WS_MPART);
  float m = 0.f;
  #pragma unroll
  for (int p = 0; p < 8; ++p)
    m += mp[(((n*8 + p)*3 + s)*32 + v)*32 + w];
  float g = 0.f;
  if (v < 25 && w < 25)
    g = A[(s*25 + v)*25 + w] + alp[0] * tanhf(m * (1.f/4800.f));
  bf16* gt = (bf16*)(ws + WS_GT);
  gt[((n*3 + s)*32 + w)*32 + v] = (bf16)g;   // transposed write
}

// ---------------- K3: graph conv + BN + residual + ReLU + sumT partials ----------------
// grid (8 seg, 64 n), 256 thr (4 waves). Chunk = 4 t, 2 barriers.
// stage1: u[s,o,v] = Wd . x_t  (B direct from XG, A hoisted), UL[t][o][s*32+v]
// stage2: y[o,w] = sum_sv u*G (G-frags hoisted from GT), fused epilogue.
__global__ __launch_bounds__(256) void k3_y(
    char* __restrict__ ws, float* __restrict__ out) {
  __shared__ __attribute__((aligned(16))) bf16 UL[4*64*104];  // [tt][o64][sv96 pad104]
  const int seg = blockIdx.x, n = blockIdx.y;
  const int tid = threadIdx.x;
  const int lane = tid & 63, wv = tid >> 6;
  const int l15 = lane & 15, l4 = lane >> 4;
  const int t0 = seg*38, tlen = min(38, 300 - t0);
  const bf16* XG = (const bf16*)(ws + WS_XG);
  const bf16* wd = (const bf16*)(ws + WS_WD);
  const bf16* gt = (const bf16*)(ws + WS_GT);
  const float* cA = (const float*)(ws + WS_COEFA);
  const float* cB = (const float*)(ws + WS_COEFB);
  const f32x4 z4 = {0.f,0.f,0.f,0.f};

  // stage1 A-frags: wave owns rt = 3*wv + q  (rt -> s = rt>>2, ot1 = rt&3)
  bf16x8 Wfr[3][2];
  #pragma unroll
  for (int q = 0; q < 3; ++q) {
    const int rt = wv*3 + q, s = rt >> 2, ot1 = rt & 3;
    #pragma unroll
    for (int kk = 0; kk < 2; ++kk)
      Wfr[q][kk] = *(const bf16x8*)&wd[(s*64 + ot1*16 + l15)*64 + kk*32 + 8*l4];
  }
  // stage2 B-frags from GT (per-n constant)
  bf16x8 Gfr[2][3];
  #pragma unroll
  for (int wt = 0; wt < 2; ++wt)
    #pragma unroll
    for (int s = 0; s < 3; ++s)
      Gfr[wt][s] = *(const bf16x8*)&gt[((n*3 + s)*32 + wt*16 + l15)*32 + 8*l4];

  const int o0 = wv*16 + 4*l4;
  float cAr[4], cBr[4];
  #pragma unroll
  for (int r = 0; r < 4; ++r) { cAr[r] = cA[o0 + r]; cBr[r] = cB[o0 + r]; }
  float st[2][4] = {{0.f,0.f,0.f,0.f},{0.f,0.f,0.f,0.f}};
  const int nch = (tlen + 3) >> 2;

  for (int ch = 0; ch < nch; ++ch) {
    // stage1: all 4 t, my 3 row-tiles
    #pragma unroll
    for (int tt = 0; tt < 4; ++tt) {
      const int t = t0 + ch*4 + tt;     // over-reads land in ws pad (discarded)
      #pragma unroll
      for (int vt = 0; vt < 2; ++vt) {
        f32x4 acc[3]; acc[0]=z4; acc[1]=z4; acc[2]=z4;
        #pragma unroll
        for (int kk = 0; kk < 2; ++kk) {
          bf16x8 B = *(const bf16x8*)&XG[((size_t)(n*300 + t)*25 + vt*16 + l15)*64 + kk*32 + 8*l4];
          #pragma unroll
          for (int q = 0; q < 3; ++q) acc[q] = mfma16(Wfr[q][kk], B, acc[q]);
        }
        #pragma unroll
        for (int q = 0; q < 3; ++q) {
          const int rt = wv*3 + q, s = rt >> 2, ot1 = rt & 3;
          #pragma unroll
          for (int r = 0; r < 4; ++r)
            UL[(tt*64 + ot1*16 + 4*l4 + r)*104 + s*32 + vt*16 + l15] = (bf16)acc[q][r];
        }
      }
    }
    __syncthreads();
    // stage2 + epilogue: my o-tile (ot = wv), all 4 t
    #pragma unroll
    for (int tt = 0; tt < 4; ++tt) {
      const int tl = ch*4 + tt;
      f32x4 acc2[2]; acc2[0] = z4; acc2[1] = z4;
      #pragma unroll
      for (int s = 0; s < 3; ++s) {
        bf16x8 Aa = *(const bf16x8*)&UL[(tt*64 + wv*16 + l15)*104 + s*32 + 8*l4];
        acc2[0] = mfma16(Aa, Gfr[0][s], acc2[0]);
        acc2[1] = mfma16(Aa, Gfr[1][s], acc2[1]);
      }
      if (tl < tlen) {
        const int t = t0 + tl;
        #pragma unroll
        for (int wt = 0; wt < 2; ++wt) {
          const int w = wt*16 + l15;
          if (w < 25) {
            bf16x4 rx = *(const bf16x4*)&XG[((size_t)(n*300 + t)*25 + w)*64 + o0];
            #pragma unroll
            for (int r = 0; r < 4; ++r) {
              float val = acc2[wt][r]*cAr[r] + cBr[r] + (float)rx[r];
              val = fmaxf(val, 0.f);
              out[((size_t)(n*64 + o0 + r)*300 + t)*25 + w] = val;
              st[wt][r] += val;
            }
          }
        }
      }
    }
    __syncthreads();
  }
  float* stp = (float*)(ws + WS_STP);
  #pragma unroll
  for (int wt = 0; wt < 2; ++wt) {
    const int w = wt*16 + l15;
    if (w < 25) {
      #pragma unroll
      for (int r = 0; r < 4; ++r)
        stp[((n*8 + seg)*64 + o0 + r)*25 + w] = st[wt][r];
    }
  }
}

// ---------------- K4: se1 (spatial attention weights) ----------------
__global__ __launch_bounds__(256) void k4_se1(
    const float* __restrict__ Wsa, const float* __restrict__ bsa,
    char* __restrict__ ws) {
  __shared__ float Sm[64][26];
  __shared__ float red[25][8];
  int n = blockIdx.x, tid = threadIdx.x;
  const float* stp = (const float*)(ws + WS_STP);
  for (int f = tid; f < 1600; f += 256) {
    int c = f / 25, v = f % 25;
    float s = 0.f;
    #pragma unroll
    for (int p = 0; p < 8; ++p) s += stp[((n*8 + p)*64 + c)*25 + v];
    Sm[c][v] = s * (1.f/300.f);
  }
  __syncthreads();
  float acc = 0.f;
  int v = tid >> 3, part = tid & 7;
  if (tid < 200) {
    for (int c = part; c < 64; c += 8) {
      #pragma unroll
      for (int k = 0; k < 25; ++k) {
        int vv = v + k - 12;
        if (vv >= 0 && vv < 25) acc += Wsa[c*25 + k] * Sm[c][vv];
      }
    }
    red[v][part] = acc;
  }
  __syncthreads();
  if (tid < 25) {
    float a = bsa[0];
    #pragma unroll
    for (int p = 0; p < 8; ++p) a += red[tid][p];
    ((float*)(ws + WS_SE1))[n*32 + tid] = 1.f + 1.f/(1.f + expf(-a));
  }
}

// ---------------- K5: weighted sum over V ----------------
__global__ __launch_bounds__(256) void k5_sv(
    const float* __restrict__ y, char* __restrict__ ws) {
  __shared__ float w1[25];
  int c = blockIdx.x, n = blockIdx.y, tid = threadIdx.x;
  if (tid < 25) w1[tid] = ((const float*)(ws + WS_SE1))[n*32 + tid];
  __syncthreads();
  float* svp = (float*)(ws + WS_SVP);
  for (int t = tid; t < 300; t += 256) {
    const float* row = y + ((size_t)(n*64 + c)*300 + t)*25;
    float acc = 0.f;
    #pragma unroll
    for (int v = 0; v < 25; ++v) acc += row[v] * w1[v];
    svp[(n*64 + c)*300 + t] = acc;
  }
}

// ---------------- K6a: se2 (temporal attention weights) ----------------
__global__ __launch_bounds__(320) void k6a_se2(
    const float* __restrict__ Wta, const float* __restrict__ bta,
    char* __restrict__ ws) {
  __shared__ float WLa[576];
  int n = blockIdx.x, tid = threadIdx.x;
  for (int f = tid; f < 576; f += 320) WLa[f] = Wta[f];
  __syncthreads();
  const float* svp = (const float*)(ws + WS_SVP);
  if (tid < 300) {
    float acc = 0.f;
    for (int c = 0; c < 64; ++c) {
      const float* rowp = svp + (n*64 + c)*300;
      #pragma unroll
      for (int k = 0; k < 9; ++k) {
        int t2 = tid + k - 4;
        if (t2 >= 0 && t2 < 300) acc += WLa[c*9 + k] * rowp[t2];
      }
    }
    float a = acc * (1.f/25.f) + bta[0];
    ((float*)(ws + WS_SE2))[n*300 + tid] = 1.f + 1.f/(1.f + expf(-a));
  }
}

// ---------------- K6b: se3 (channel attention, squeeze-excite) ----------------
__global__ __launch_bounds__(256) void k6b_se3(
    const float* __restrict__ Wfc1, const float* __restrict__ bfc1,
    const float* __restrict__ Wfc2, const float* __restrict__ bfc2,
    char* __restrict__ ws) {
  __shared__ float stv[64][4];
  __shared__ float m[64];
  __shared__ float h[32];
  int n = blockIdx.x, tid = threadIdx.x;
  const float* svp = (const float*)(ws + WS_SVP);
  const float* w2 = (const float*)(ws + WS_SE2) + n*300;
  {
    int c = tid & 63, p = tid >> 6;
    float acc = 0.f;
    for (int t = p*75; t < p*75 + 75; ++t)
      acc += w2[t] * svp[(n*64 + c)*300 + t];
    stv[c][p] = acc;
  }
  __syncthreads();
  if (tid < 64) m[tid] = (stv[tid][0]+stv[tid][1]+stv[tid][2]+stv[tid][3]) * (1.f/7500.f);
  __syncthreads();
  if (tid < 32) {
    float a = bfc1[tid];
    for (int c = 0; c < 64; ++c) a += Wfc1[tid*64 + c] * m[c];
    h[tid] = fmaxf(a, 0.f);
  }
  __syncthreads();
  if (tid < 64) {
    float a = bfc2[tid];
    #pragma unroll
    for (int j = 0; j < 32; ++j) a += Wfc2[tid*32 + j] * h[j];
    ((float*)(ws + WS_SE3))[n*64 + tid] = 1.f + 1.f/(1.f + expf(-a));
  }
}

// ---------------- K7: final elementwise scale (in-place on d_out) ----------------
__global__ __launch_bounds__(256) void k7_scale(
    float* __restrict__ out, const char* __restrict__ ws) {
  int g = blockIdx.x*256 + threadIdx.x;
  long e0 = (long)g * 4;
  if (e0 >= 30720000L) return;
  const float* w1 = (const float*)(ws + WS_SE1);
  const float* w2 = (const float*)(ws + WS_SE2);
  const float* w3 = (const float*)(ws + WS_SE3);
  float4 val = *(const float4*)(out + e0);
  float r[4] = {val.x, val.y, val.z, val.w};
  #pragma unroll
  for (int j = 0; j < 4; ++j) {
    long e = e0 + j;
    int v = (int)(e % 25);
    long q = e / 25;
    int t = (int)(q % 300);
    long q2 = q / 300;
    int c = (int)(q2 & 63);
    int n = (int)(q2 >> 6);
    r[j] *= w1[n*32 + v] * w2[n*300 + t] * w3[n*64 + c];
  }
  float4 ov = {r[0], r[1], r[2], r[3]};
  *(float4*)(out + e0) = ov;
}

extern "C" void kernel_launch(void* const* d_in, const int* in_sizes, int n_in,
                              void* d_out, int out_size, void* d_ws, size_t ws_size,
                              hipStream_t stream) {
  const float* x    = (const float*)d_in[0];
  const float* A    = (const float*)d_in[1];
  const float* alp  = (const float*)d_in[2];
  const float* Wa   = (const float*)d_in[3];
  const float* ba   = (const float*)d_in[4];
  const float* Wb   = (const float*)d_in[5];
  const float* bb   = (const float*)d_in[6];
  const float* Wd   = (const float*)d_in[7];
  const float* bd   = (const float*)d_in[8];
  const float* gam  = (const float*)d_in[9];
  const float* bet  = (const float*)d_in[10];
  const float* mean = (const float*)d_in[11];
  const float* var  = (const float*)d_in[12];
  const float* Wsa  = (const float*)d_in[13];
  const float* bsa  = (const float*)d_in[14];
  const float* Wta  = (const float*)d_in[15];
  const float* bta  = (const float*)d_in[16];
  const float* Wfc1 = (const float*)d_in[17];
  const float* bfc1 = (const float*)d_in[18];
  const float* Wfc2 = (const float*)d_in[19];
  const float* bfc2 = (const float*)d_in[20];
  char* ws = (char*)d_ws;
  float* out = (float*)d_out;

  k_prep<<<dim3(1), dim3(256), 0, stream>>>(Wa, Wb, Wd, bd, gam, bet, mean, var, ws);
  k_tr<<<dim3(19, 64), dim3(256), 0, stream>>>(x, ws);
  k1_m<<<dim3(8, 64), dim3(256), 0, stream>>>(ba, bb, ws);
  k1b_g<<<dim3(768), dim3(256), 0, stream>>>(A, alp, ws);
  k3_y<<<dim3(8, 64), dim3(256), 0, stream>>>(ws, out);
  k4_se1<<<dim3(64), dim3(256), 0, stream>>>(Wsa, bsa, ws);
  k5_sv<<<dim3(64, 64), dim3(256), 0, stream>>>(out, ws);
  k6a_se2<<<dim3(64), dim3(320), 0, stream>>>(Wta, bta, ws);
  k6b_se3<<<dim3(64), dim3(256), 0, stream>>>(Wfc1, bfc1, Wfc2, bfc2, ws);
  k7_scale<<<dim3(30000), dim3(256), 0, stream>>>(out, ws);
}

// Round 3
// 291.836 us; speedup vs baseline: 1.8806x; 1.1604x over previous
//
#include <hip/hip_runtime.h>

// Problem sizes: N=64, C=64, T=300, V=25, S=3, inter=16
typedef __bf16 bf16;
typedef bf16 bf16x8 __attribute__((ext_vector_type(8)));
typedef bf16 bf16x4 __attribute__((ext_vector_type(4)));
typedef float f32x4 __attribute__((ext_vector_type(4)));

// ---- workspace byte offsets (total ~74.6 MB) ----
#define WS_XG    0u           // bf16 [64][300][25][64]  XG[n][t][v][c], +64KB pad
#define WS_WAB   61505536u    // bf16 [3][32][64]   rows 0-15=Wa, 16-31=Wb
#define WS_WD    61517824u    // bf16 [3][64][64]
#define WS_COEFA 61542400u    // f32  [64]  bn scale
#define WS_COEFB 61542656u    // f32  [64]  bn bias (incl. bd-sum)
#define WS_GT    61542912u    // bf16 [64][3][32][32]  GT[w][v]=G[v][w], zero-padded
#define WS_MPART 61936128u    // f32  [64][16][3][32][32] M partials (dead after k1b)
#define WS_STP   61936128u    // f32  [64][16][64][25]  sum-over-t(y) partials (union w/ MPART)
#define WS_SE1   74519040u    // f32  [64][32]   1+se1[v]
#define WS_SE2   74527232u    // f32  [64][304]  1+se2[t]
#define WS_SE3   74605056u    // f32  [64][64]   1+se3[c]

__device__ __forceinline__ f32x4 mfma16(bf16x8 a, bf16x8 b, f32x4 c) {
  return __builtin_amdgcn_mfma_f32_16x16x32_bf16(a, b, c, 0, 0, 0);
}

// ---------------- P0: weight prep ----------------
__global__ __launch_bounds__(256) void k_prep(
    const float* __restrict__ Wa, const float* __restrict__ Wb,
    const float* __restrict__ Wd, const float* __restrict__ bd,
    const float* __restrict__ gam, const float* __restrict__ bet,
    const float* __restrict__ mean, const float* __restrict__ var,
    char* __restrict__ ws) {
  bf16* wab = (bf16*)(ws + WS_WAB);
  bf16* wd  = (bf16*)(ws + WS_WD);
  float* cA = (float*)(ws + WS_COEFA);
  float* cB = (float*)(ws + WS_COEFB);
  int tid = threadIdx.x;
  for (int f = tid; f < 3*32*64; f += 256) {
    int s = f >> 11, r = (f >> 6) & 31, c = f & 63;
    float v = (r < 16) ? Wa[(s*16 + r)*64 + c] : Wb[(s*16 + (r-16))*64 + c];
    wab[f] = (bf16)v;
  }
  for (int f = tid; f < 3*64*64; f += 256) wd[f] = (bf16)Wd[f];
  if (tid < 64) {
    float bds = bd[tid] + bd[64+tid] + bd[128+tid];
    float iv = gam[tid] / sqrtf(var[tid] + 1e-5f);
    cA[tid] = iv;
    cB[tid] = (bds - mean[tid]) * iv + bet[tid];
  }
}

// ---------------- k_tr: transpose x[n][c][t][v] f32 -> XG[n][t][v][c] bf16 ----------------
__global__ __launch_bounds__(256) void k_tr(
    const float* __restrict__ x, char* __restrict__ ws) {
  __shared__ __attribute__((aligned(16))) bf16 tile[64*410];  // [c][flat tv 400, pad 410]
  const int tc = blockIdx.x, n = blockIdx.y, tid = threadIdx.x;
  const int t0 = tc*16;
  const int vmax = min(400, 7500 - t0*25);
  bf16* XG = (bf16*)(ws + WS_XG);
  for (int u = tid; u < 6400; u += 256) {
    int c = u / 100, q = u % 100;
    int idx = 4*q;
    if (idx < vmax) {
      float4 val = *(const float4*)(x + (size_t)(n*64 + c)*7500 + t0*25 + idx);
      bf16* p = &tile[c*410 + idx];
      p[0] = (bf16)val.x; p[1] = (bf16)val.y; p[2] = (bf16)val.z; p[3] = (bf16)val.w;
    }
  }
  __syncthreads();
  for (int k = 0; k < 16; ++k) {
    int u = tid + k*256;
    int c8 = u & 7, v = (u >> 3) & 31, dt = u >> 8;
    int t = t0 + dt;
    if (v < 25 && t < 300) {
      bf16x8 pk;
      #pragma unroll
      for (int j = 0; j < 8; ++j) pk[j] = tile[(c8*8 + j)*410 + dt*25 + v];
      *(bf16x8*)&XG[((size_t)(n*300 + t)*25 + v)*64 + c8*8] = pk;
    }
  }
}

// ---------------- K1: fused a,b projection + M partial accumulation ----------------
// grid (16 seg, 64 n), 256 thr (4 waves). Chunk = 4 t, wave owns one t for stage1.
__global__ __launch_bounds__(256) void k1_m(
    const float* __restrict__ ba_g, const float* __restrict__ bb_g,
    char* __restrict__ ws) {
  __shared__ __attribute__((aligned(16))) bf16 AB[6*32*72];   // [s*2+ab][v32][k64 pad72]
  const int seg = blockIdx.x, n = blockIdx.y;
  const int tid = threadIdx.x;
  const int lane = tid & 63, wv = tid >> 6;
  const int l15 = lane & 15, l4 = lane >> 4;
  const int t0 = seg*19, tlen = min(19, 300 - t0);
  const bf16* XG  = (const bf16*)(ws + WS_XG);
  const bf16* wab = (const bf16*)(ws + WS_WAB);
  const f32x4 z4 = {0.f,0.f,0.f,0.f};

  bf16x8 Afr[6][2];
  float bias[6][4];
  #pragma unroll
  for (int rt = 0; rt < 6; ++rt) {
    const int s = rt >> 1, abk = rt & 1;
    #pragma unroll
    for (int kk = 0; kk < 2; ++kk)
      Afr[rt][kk] = *(const bf16x8*)&wab[(s*32 + abk*16 + l15)*64 + kk*32 + 8*l4];
    const float* bp = abk ? bb_g : ba_g;
    #pragma unroll
    for (int r = 0; r < 4; ++r) bias[rt][r] = bp[s*16 + 4*l4 + r];
  }
  f32x4 macc[3]; macc[0]=z4; macc[1]=z4; macc[2]=z4;
  const int vt2 = wv >> 1, wt2 = wv & 1;
  const int nch = (tlen + 3) >> 2;

  for (int ch = 0; ch < nch; ++ch) {
    const int tl = ch*4 + wv;
    const int t = t0 + tl;            // over-reads (<1 t-row) land in ws pad, discarded
    const bool tv = (tl < tlen);
    #pragma unroll
    for (int vt = 0; vt < 2; ++vt) {
      f32x4 acc[6];
      #pragma unroll
      for (int rt = 0; rt < 6; ++rt) acc[rt] = z4;
      #pragma unroll
      for (int kk = 0; kk < 2; ++kk) {
        bf16x8 B = *(const bf16x8*)&XG[((size_t)(n*300 + t)*25 + vt*16 + l15)*64 + kk*32 + 8*l4];
        #pragma unroll
        for (int rt = 0; rt < 6; ++rt) acc[rt] = mfma16(Afr[rt][kk], B, acc[rt]);
      }
      #pragma unroll
      for (int rt = 0; rt < 6; ++rt) {
        bf16x4 pk;
        #pragma unroll
        for (int r = 0; r < 4; ++r)
          pk[r] = (bf16)(tv ? (acc[rt][r] + bias[rt][r]) : 0.f);
        *(bf16x4*)&AB[(rt*32 + vt*16 + l15)*72 + wv*16 + 4*l4] = pk;
      }
    }
    __syncthreads();
    #pragma unroll
    for (int s = 0; s < 3; ++s) {
      #pragma unroll
      for (int kk = 0; kk < 2; ++kk) {
        bf16x8 Aa = *(const bf16x8*)&AB[((s*2 + 0)*32 + vt2*16 + l15)*72 + kk*32 + 8*l4];
        bf16x8 Bb = *(const bf16x8*)&AB[((s*2 + 1)*32 + wt2*16 + l15)*72 + kk*32 + 8*l4];
        macc[s] = mfma16(Aa, Bb, macc[s]);
      }
    }
    __syncthreads();
  }
  float* mp = (float*)(ws + WS_MPART);
  #pragma unroll
  for (int s = 0; s < 3; ++s) {
    #pragma unroll
    for (int r = 0; r < 4; ++r) {
      int v = vt2*16 + 4*l4 + r, w = wt2*16 + l15;
      mp[(((n*16 + seg)*3 + s)*32 + v)*32 + w] = macc[s][r];
    }
  }
}

// ---------------- K1b: reduce M partials -> GT (bf16, transposed, zero-padded) ----------------
__global__ __launch_bounds__(256) void k1b_g(
    const float* __restrict__ A, const float* __restrict__ alp,
    char* __restrict__ ws) {
  int e = blockIdx.x*256 + threadIdx.x;   // 196608 exact
  int w = e & 31, v = (e >> 5) & 31;
  int s = (e >> 10) % 3, n = e / 3072;
  const float* mp = (const float*)(ws + WS_MPART);
  float m = 0.f;
  #pragma unroll
  for (int p = 0; p < 16; ++p)
    m += mp[(((n*16 + p)*3 + s)*32 + v)*32 + w];
  float g = 0.f;
  if (v < 25 && w < 25)
    g = A[(s*25 + v)*25 + w] + alp[0] * tanhf(m * (1.f/4800.f));
  bf16* gt = (bf16*)(ws + WS_GT);
  gt[((n*3 + s)*32 + w)*32 + v] = (bf16)g;   // transposed write
}

// ---------------- K3: graph conv + BN + residual + ReLU + sumT partials ----------------
// grid (16 seg, 64 n), 256 thr (4 waves). Chunk = 2 t, 2 barriers. UL 26.6 KB -> 4 blk/CU.
__global__ __launch_bounds__(256) void k3_y(
    char* __restrict__ ws, float* __restrict__ out) {
  __shared__ __attribute__((aligned(16))) bf16 UL[2*64*104];  // [tt][o64][sv96 pad104]
  const int seg = blockIdx.x, n = blockIdx.y;
  const int tid = threadIdx.x;
  const int lane = tid & 63, wv = tid >> 6;
  const int l15 = lane & 15, l4 = lane >> 4;
  const int t0 = seg*19, tlen = min(19, 300 - t0);
  const bf16* XG = (const bf16*)(ws + WS_XG);
  const bf16* wd = (const bf16*)(ws + WS_WD);
  const bf16* gt = (const bf16*)(ws + WS_GT);
  const float* cA = (const float*)(ws + WS_COEFA);
  const float* cB = (const float*)(ws + WS_COEFB);
  const f32x4 z4 = {0.f,0.f,0.f,0.f};

  bf16x8 Wfr[3][2];
  #pragma unroll
  for (int q = 0; q < 3; ++q) {
    const int rt = wv*3 + q, s = rt >> 2, ot1 = rt & 3;
    #pragma unroll
    for (int kk = 0; kk < 2; ++kk)
      Wfr[q][kk] = *(const bf16x8*)&wd[(s*64 + ot1*16 + l15)*64 + kk*32 + 8*l4];
  }
  bf16x8 Gfr[2][3];
  #pragma unroll
  for (int wt = 0; wt < 2; ++wt)
    #pragma unroll
    for (int s = 0; s < 3; ++s)
      Gfr[wt][s] = *(const bf16x8*)&gt[((n*3 + s)*32 + wt*16 + l15)*32 + 8*l4];

  const int o0 = wv*16 + 4*l4;
  float cAr[4], cBr[4];
  #pragma unroll
  for (int r = 0; r < 4; ++r) { cAr[r] = cA[o0 + r]; cBr[r] = cB[o0 + r]; }
  float st[2][4] = {{0.f,0.f,0.f,0.f},{0.f,0.f,0.f,0.f}};
  const int nch = (tlen + 1) >> 1;

  for (int ch = 0; ch < nch; ++ch) {
    #pragma unroll
    for (int tt = 0; tt < 2; ++tt) {
      const int t = t0 + ch*2 + tt;     // over-reads land in ws pad / next seg, discarded
      #pragma unroll
      for (int vt = 0; vt < 2; ++vt) {
        f32x4 acc[3]; acc[0]=z4; acc[1]=z4; acc[2]=z4;
        #pragma unroll
        for (int kk = 0; kk < 2; ++kk) {
          bf16x8 B = *(const bf16x8*)&XG[((size_t)(n*300 + t)*25 + vt*16 + l15)*64 + kk*32 + 8*l4];
          #pragma unroll
          for (int q = 0; q < 3; ++q) acc[q] = mfma16(Wfr[q][kk], B, acc[q]);
        }
        #pragma unroll
        for (int q = 0; q < 3; ++q) {
          const int rt = wv*3 + q, s = rt >> 2, ot1 = rt & 3;
          #pragma unroll
          for (int r = 0; r < 4; ++r)
            UL[(tt*64 + ot1*16 + 4*l4 + r)*104 + s*32 + vt*16 + l15] = (bf16)acc[q][r];
        }
      }
    }
    __syncthreads();
    #pragma unroll
    for (int tt = 0; tt < 2; ++tt) {
      const int tl = ch*2 + tt;
      f32x4 acc2[2]; acc2[0] = z4; acc2[1] = z4;
      #pragma unroll
      for (int s = 0; s < 3; ++s) {
        bf16x8 Aa = *(const bf16x8*)&UL[(tt*64 + wv*16 + l15)*104 + s*32 + 8*l4];
        acc2[0] = mfma16(Aa, Gfr[0][s], acc2[0]);
        acc2[1] = mfma16(Aa, Gfr[1][s], acc2[1]);
      }
      if (tl < tlen) {
        const int t = t0 + tl;
        #pragma unroll
        for (int wt = 0; wt < 2; ++wt) {
          const int w = wt*16 + l15;
          if (w < 25) {
            bf16x4 rx = *(const bf16x4*)&XG[((size_t)(n*300 + t)*25 + w)*64 + o0];
            #pragma unroll
            for (int r = 0; r < 4; ++r) {
              float val = acc2[wt][r]*cAr[r] + cBr[r] + (float)rx[r];
              val = fmaxf(val, 0.f);
              out[((size_t)(n*64 + o0 + r)*300 + t)*25 + w] = val;
              st[wt][r] += val;
            }
          }
        }
      }
    }
    __syncthreads();
  }
  float* stp = (float*)(ws + WS_STP);
  #pragma unroll
  for (int wt = 0; wt < 2; ++wt) {
    const int w = wt*16 + l15;
    if (w < 25) {
      #pragma unroll
      for (int r = 0; r < 4; ++r)
        stp[((n*16 + seg)*64 + o0 + r)*25 + w] = st[wt][r];
    }
  }
}

// ---------------- k_att: fused se1 + svp(LDS) + se2 + se3 ----------------
// grid 64 (one block per n), 1024 threads (16 waves).
__global__ __launch_bounds__(1024) void k_att(
    const float* __restrict__ Wsa, const float* __restrict__ bsa,
    const float* __restrict__ Wta, const float* __restrict__ bta,
    const float* __restrict__ Wfc1, const float* __restrict__ bfc1,
    const float* __restrict__ Wfc2, const float* __restrict__ bfc2,
    const float* __restrict__ y, char* __restrict__ ws) {
  __shared__ float Sm[64][26];
  __shared__ float red0[25][8];
  __shared__ float w1[25];
  __shared__ bf16 Sv[64][304];
  __shared__ float WLa[576];
  __shared__ float redt[304][4];
  __shared__ float w2s[304];
  __shared__ float red2[64][16];
  __shared__ float mS[64];
  __shared__ float hS[32];
  const int n = blockIdx.x, tid = threadIdx.x;
  const float* stp = (const float*)(ws + WS_STP);

  // phase 0: se1 from stp (mean over t via 16 seg partials)
  for (int f = tid; f < 1600; f += 1024) {
    int c = f / 25, v = f % 25;
    float s = 0.f;
    #pragma unroll
    for (int p = 0; p < 16; ++p) s += stp[((n*16 + p)*64 + c)*25 + v];
    Sm[c][v] = s * (1.f/300.f);
  }
  for (int f = tid; f < 576; f += 1024) WLa[f] = Wta[f];
  __syncthreads();
  if (tid < 200) {
    int v = tid >> 3, part = tid & 7;
    float acc = 0.f;
    for (int c = part; c < 64; c += 8) {
      #pragma unroll
      for (int k = 0; k < 25; ++k) {
        int vv = v + k - 12;
        if (vv >= 0 && vv < 25) acc += Wsa[c*25 + k] * Sm[c][vv];
      }
    }
    red0[v][part] = acc;
  }
  __syncthreads();
  if (tid < 25) {
    float a = bsa[0];
    #pragma unroll
    for (int p = 0; p < 8; ++p) a += red0[tid][p];
    float f1 = 1.f + 1.f/(1.f + expf(-a));
    w1[tid] = f1;
    ((float*)(ws + WS_SE1))[n*32 + tid] = f1;
  }
  __syncthreads();
  // phase 1: Sv[c][t] = sum_v y*(1+se1[v])  (svp, LDS-only)
  for (int u = tid; u < 19200; u += 1024) {
    int c = u / 300, t = u % 300;
    const float* row = y + ((size_t)(n*64 + c)*300 + t)*25;
    float acc = 0.f;
    #pragma unroll
    for (int v = 0; v < 25; ++v) acc += row[v] * w1[v];
    Sv[c][t] = (bf16)acc;
  }
  __syncthreads();
  // phase 2: se2 temporal conv (c-split 4 partials x 300 t)
  for (int u = tid; u < 1200; u += 1024) {
    int t = u >> 2, part = u & 3;
    float acc = 0.f;
    for (int c = part*16; c < part*16 + 16; ++c) {
      #pragma unroll
      for (int k = 0; k < 9; ++k) {
        int t2 = t + k - 4;
        if (t2 >= 0 && t2 < 300) acc += WLa[c*9 + k] * (float)Sv[c][t2];
      }
    }
    redt[t][part] = acc;
  }
  __syncthreads();
  if (tid < 300) {
    float a = (redt[tid][0] + redt[tid][1] + redt[tid][2] + redt[tid][3]) * (1.f/25.f) + bta[0];
    float f2 = 1.f + 1.f/(1.f + expf(-a));
    w2s[tid] = f2;
    ((float*)(ws + WS_SE2))[n*304 + tid] = f2;
  }
  __syncthreads();
  // phase 3: se3 squeeze-excite
  {
    int c = tid & 63, part = tid >> 6;
    int tb = part*19, te = min(tb + 19, 300);
    float acc = 0.f;
    for (int t = tb; t < te; ++t) acc += w2s[t] * (float)Sv[c][t];
    red2[c][part] = acc;
  }
  __syncthreads();
  if (tid < 64) {
    float mm = 0.f;
    #pragma unroll
    for (int p = 0; p < 16; ++p) mm += red2[tid][p];
    mS[tid] = mm * (1.f/7500.f);
  }
  __syncthreads();
  if (tid < 32) {
    float a = bfc1[tid];
    for (int c = 0; c < 64; ++c) a += Wfc1[tid*64 + c] * mS[c];
    hS[tid] = fmaxf(a, 0.f);
  }
  __syncthreads();
  if (tid < 64) {
    float a = bfc2[tid];
    #pragma unroll
    for (int j = 0; j < 32; ++j) a += Wfc2[tid*32 + j] * hS[j];
    ((float*)(ws + WS_SE3))[n*64 + tid] = 1.f + 1.f/(1.f + expf(-a));
  }
}

// ---------------- K7: final elementwise scale (in-place on d_out), int32 math ----------------
__global__ __launch_bounds__(256) void k7_scale(
    float* __restrict__ out, const char* __restrict__ ws) {
  int g = blockIdx.x*256 + threadIdx.x;
  int e0 = g * 4;
  if (e0 >= 30720000) return;
  const float* w1 = (const float*)(ws + WS_SE1);
  const float* w2 = (const float*)(ws + WS_SE2);
  const float* w3 = (const float*)(ws + WS_SE3);
  float4 val = *(const float4*)(out + e0);
  float r[4] = {val.x, val.y, val.z, val.w};
  #pragma unroll
  for (int j = 0; j < 4; ++j) {
    int e = e0 + j;
    int v = e % 25;
    int q = e / 25;
    int t = q % 300;
    int q2 = q / 300;
    int c = q2 & 63;
    int n = q2 >> 6;
    r[j] *= w1[n*32 + v] * w2[n*304 + t] * w3[n*64 + c];
  }
  float4 ov = {r[0], r[1], r[2], r[3]};
  *(float4*)(out + e0) = ov;
}

extern "C" void kernel_launch(void* const* d_in, const int* in_sizes, int n_in,
                              void* d_out, int out_size, void* d_ws, size_t ws_size,
                              hipStream_t stream) {
  const float* x    = (const float*)d_in[0];
  const float* A    = (const float*)d_in[1];
  const float* alp  = (const float*)d_in[2];
  const float* Wa   = (const float*)d_in[3];
  const float* ba   = (const float*)d_in[4];
  const float* Wb   = (const float*)d_in[5];
  const float* bb   = (const float*)d_in[6];
  const float* Wd   = (const float*)d_in[7];
  const float* bd   = (const float*)d_in[8];
  const float* gam  = (const float*)d_in[9];
  const float* bet  = (const float*)d_in[10];
  const float* mean = (const float*)d_in[11];
  const float* var  = (const float*)d_in[12];
  const float* Wsa  = (const float*)d_in[13];
  const float* bsa  = (const float*)d_in[14];
  const float* Wta  = (const float*)d_in[15];
  const float* bta  = (const float*)d_in[16];
  const float* Wfc1 = (const float*)d_in[17];
  const float* bfc1 = (const float*)d_in[18];
  const float* Wfc2 = (const float*)d_in[19];
  const float* bfc2 = (const float*)d_in[20];
  char* ws = (char*)d_ws;
  float* out = (float*)d_out;

  k_prep<<<dim3(1), dim3(256), 0, stream>>>(Wa, Wb, Wd, bd, gam, bet, mean, var, ws);
  k_tr<<<dim3(19, 64), dim3(256), 0, stream>>>(x, ws);
  k1_m<<<dim3(16, 64), dim3(256), 0, stream>>>(ba, bb, ws);
  k1b_g<<<dim3(768), dim3(256), 0, stream>>>(A, alp, ws);
  k3_y<<<dim3(16, 64), dim3(256), 0, stream>>>(ws, out);
  k_att<<<dim3(64), dim3(1024), 0, stream>>>(Wsa, bsa, Wta, bta, Wfc1, bfc1, Wfc2, bfc2, out, ws);
  k7_scale<<<dim3(30000), dim3(256), 0, stream>>>(out, ws);
}

// Round 4
// 271.410 us; speedup vs baseline: 2.0221x; 1.0753x over previous
//
#include <hip/hip_runtime.h>

// Problem sizes: N=64, C=64, T=300, V=25, S=3, inter=16
typedef __bf16 bf16;
typedef bf16 bf16x8 __attribute__((ext_vector_type(8)));
typedef bf16 bf16x4 __attribute__((ext_vector_type(4)));
typedef float f32x4 __attribute__((ext_vector_type(4)));

// ---- workspace byte offsets (total ~74.6 MB) ----
// XG holds x[n][t][v][c] bf16 until k3, which overwrites it in-place with y (same layout).
#define WS_XG    0u           // bf16 [64][300][25][64]  + 64KB pad
#define WS_WAB   61505536u    // bf16 [3][32][64]   rows 0-15=Wa, 16-31=Wb
#define WS_WD    61517824u    // bf16 [3][64][64]
#define WS_COEFA 61542400u    // f32  [64]  bn scale
#define WS_COEFB 61542656u    // f32  [64]  bn bias (incl. bd-sum)
#define WS_GT    61542912u    // bf16 [64][3][32][32]  GT[w][v]=G[v][w], zero-padded
#define WS_MPART 61936128u    // f32  [64][16][3][32][32] M partials (dead after k1b)
#define WS_STP   61936128u    // f32  [64][16][64][25]  sum-over-t(y) partials (union w/ MPART)
#define WS_SE1   74519040u    // f32  [64][32]   1+se1[v]
#define WS_SE2   74527232u    // f32  [64][304]  1+se2[t]
#define WS_SE3   74605056u    // f32  [64][64]   1+se3[c]

__device__ __forceinline__ f32x4 mfma16(bf16x8 a, bf16x8 b, f32x4 c) {
  return __builtin_amdgcn_mfma_f32_16x16x32_bf16(a, b, c, 0, 0, 0);
}

// ---------------- P0: weight prep ----------------
__global__ __launch_bounds__(256) void k_prep(
    const float* __restrict__ Wa, const float* __restrict__ Wb,
    const float* __restrict__ Wd, const float* __restrict__ bd,
    const float* __restrict__ gam, const float* __restrict__ bet,
    const float* __restrict__ mean, const float* __restrict__ var,
    char* __restrict__ ws) {
  bf16* wab = (bf16*)(ws + WS_WAB);
  bf16* wd  = (bf16*)(ws + WS_WD);
  float* cA = (float*)(ws + WS_COEFA);
  float* cB = (float*)(ws + WS_COEFB);
  int tid = threadIdx.x;
  for (int f = tid; f < 3*32*64; f += 256) {
    int s = f >> 11, r = (f >> 6) & 31, c = f & 63;
    float v = (r < 16) ? Wa[(s*16 + r)*64 + c] : Wb[(s*16 + (r-16))*64 + c];
    wab[f] = (bf16)v;
  }
  for (int f = tid; f < 3*64*64; f += 256) wd[f] = (bf16)Wd[f];
  if (tid < 64) {
    float bds = bd[tid] + bd[64+tid] + bd[128+tid];
    float iv = gam[tid] / sqrtf(var[tid] + 1e-5f);
    cA[tid] = iv;
    cB[tid] = (bds - mean[tid]) * iv + bet[tid];
  }
}

// ---------------- k_tr: transpose x[n][c][t][v] f32 -> XG[n][t][v][c] bf16 ----------------
__global__ __launch_bounds__(256) void k_tr(
    const float* __restrict__ x, char* __restrict__ ws) {
  __shared__ __attribute__((aligned(16))) bf16 tile[64*410];  // [c][flat tv 400, pad 410]
  const int tc = blockIdx.x, n = blockIdx.y, tid = threadIdx.x;
  const int t0 = tc*16;
  const int vmax = min(400, 7500 - t0*25);
  bf16* XG = (bf16*)(ws + WS_XG);
  for (int u = tid; u < 6400; u += 256) {
    int c = u / 100, q = u % 100;
    int idx = 4*q;
    if (idx < vmax) {
      float4 val = *(const float4*)(x + (size_t)(n*64 + c)*7500 + t0*25 + idx);
      bf16* p = &tile[c*410 + idx];
      p[0] = (bf16)val.x; p[1] = (bf16)val.y; p[2] = (bf16)val.z; p[3] = (bf16)val.w;
    }
  }
  __syncthreads();
  for (int k = 0; k < 16; ++k) {
    int u = tid + k*256;
    int c8 = u & 7, v = (u >> 3) & 31, dt = u >> 8;
    int t = t0 + dt;
    if (v < 25 && t < 300) {
      bf16x8 pk;
      #pragma unroll
      for (int j = 0; j < 8; ++j) pk[j] = tile[(c8*8 + j)*410 + dt*25 + v];
      *(bf16x8*)&XG[((size_t)(n*300 + t)*25 + v)*64 + c8*8] = pk;
    }
  }
}

// ---------------- K1: fused a,b projection + M partial accumulation ----------------
// grid (16 seg, 64 n), 256 thr (4 waves). Chunk = 4 t, wave owns one t for stage1.
__global__ __launch_bounds__(256) void k1_m(
    const float* __restrict__ ba_g, const float* __restrict__ bb_g,
    char* __restrict__ ws) {
  __shared__ __attribute__((aligned(16))) bf16 AB[6*32*72];   // [s*2+ab][v32][k64 pad72]
  const int seg = blockIdx.x, n = blockIdx.y;
  const int tid = threadIdx.x;
  const int lane = tid & 63, wv = tid >> 6;
  const int l15 = lane & 15, l4 = lane >> 4;
  const int t0 = seg*19, tlen = min(19, 300 - t0);
  const bf16* XG  = (const bf16*)(ws + WS_XG);
  const bf16* wab = (const bf16*)(ws + WS_WAB);
  const f32x4 z4 = {0.f,0.f,0.f,0.f};

  bf16x8 Afr[6][2];
  float bias[6][4];
  #pragma unroll
  for (int rt = 0; rt < 6; ++rt) {
    const int s = rt >> 1, abk = rt & 1;
    #pragma unroll
    for (int kk = 0; kk < 2; ++kk)
      Afr[rt][kk] = *(const bf16x8*)&wab[(s*32 + abk*16 + l15)*64 + kk*32 + 8*l4];
    const float* bp = abk ? bb_g : ba_g;
    #pragma unroll
    for (int r = 0; r < 4; ++r) bias[rt][r] = bp[s*16 + 4*l4 + r];
  }
  f32x4 macc[3]; macc[0]=z4; macc[1]=z4; macc[2]=z4;
  const int vt2 = wv >> 1, wt2 = wv & 1;
  const int nch = (tlen + 3) >> 2;

  for (int ch = 0; ch < nch; ++ch) {
    const int tl = ch*4 + wv;
    const int t = t0 + tl;            // over-reads (<1 t-row) land in ws pad, discarded
    const bool tv = (tl < tlen);
    #pragma unroll
    for (int vt = 0; vt < 2; ++vt) {
      f32x4 acc[6];
      #pragma unroll
      for (int rt = 0; rt < 6; ++rt) acc[rt] = z4;
      #pragma unroll
      for (int kk = 0; kk < 2; ++kk) {
        bf16x8 B = *(const bf16x8*)&XG[((size_t)(n*300 + t)*25 + vt*16 + l15)*64 + kk*32 + 8*l4];
        #pragma unroll
        for (int rt = 0; rt < 6; ++rt) acc[rt] = mfma16(Afr[rt][kk], B, acc[rt]);
      }
      #pragma unroll
      for (int rt = 0; rt < 6; ++rt) {
        bf16x4 pk;
        #pragma unroll
        for (int r = 0; r < 4; ++r)
          pk[r] = (bf16)(tv ? (acc[rt][r] + bias[rt][r]) : 0.f);
        *(bf16x4*)&AB[(rt*32 + vt*16 + l15)*72 + wv*16 + 4*l4] = pk;
      }
    }
    __syncthreads();
    #pragma unroll
    for (int s = 0; s < 3; ++s) {
      #pragma unroll
      for (int kk = 0; kk < 2; ++kk) {
        bf16x8 Aa = *(const bf16x8*)&AB[((s*2 + 0)*32 + vt2*16 + l15)*72 + kk*32 + 8*l4];
        bf16x8 Bb = *(const bf16x8*)&AB[((s*2 + 1)*32 + wt2*16 + l15)*72 + kk*32 + 8*l4];
        macc[s] = mfma16(Aa, Bb, macc[s]);
      }
    }
    __syncthreads();
  }
  float* mp = (float*)(ws + WS_MPART);
  #pragma unroll
  for (int s = 0; s < 3; ++s) {
    #pragma unroll
    for (int r = 0; r < 4; ++r) {
      int v = vt2*16 + 4*l4 + r, w = wt2*16 + l15;
      mp[(((n*16 + seg)*3 + s)*32 + v)*32 + w] = macc[s][r];
    }
  }
}

// ---------------- K1b: reduce M partials -> GT (bf16, transposed, zero-padded) ----------------
__global__ __launch_bounds__(256) void k1b_g(
    const float* __restrict__ A, const float* __restrict__ alp,
    char* __restrict__ ws) {
  int e = blockIdx.x*256 + threadIdx.x;   // 196608 exact
  int w = e & 31, v = (e >> 5) & 31;
  int s = (e >> 10) % 3, n = e / 3072;
  const float* mp = (const float*)(ws + WS_MPART);
  float m = 0.f;
  #pragma unroll
  for (int p = 0; p < 16; ++p)
    m += mp[(((n*16 + p)*3 + s)*32 + v)*32 + w];
  float g = 0.f;
  if (v < 25 && w < 25)
    g = A[(s*25 + v)*25 + w] + alp[0] * tanhf(m * (1.f/4800.f));
  bf16* gt = (bf16*)(ws + WS_GT);
  gt[((n*3 + s)*32 + w)*32 + v] = (bf16)g;   // transposed write
}

// ---------------- K3: graph conv + BN + residual + ReLU; y -> bf16 IN-PLACE over XG ----------------
// grid (16 seg, 64 n), 256 thr (4 waves). Chunk = 2 t, 3 barriers.
// In-place safety: all XG reads of a chunk (stage1 B-frags, residual) complete before the
// write barrier; writes touch only rows [t0, t0+tlen) of this block's segment. Cross-block
// over-reads (v>=25 spill, t0+tlen row) feed only GT's zero-padded columns or guarded-out tiles.
__global__ __launch_bounds__(256) void k3_y(char* __restrict__ ws) {
  __shared__ __attribute__((aligned(16))) bf16 UL[2*64*104];  // [tt][o64][sv96 pad104]
  const int seg = blockIdx.x, n = blockIdx.y;
  const int tid = threadIdx.x;
  const int lane = tid & 63, wv = tid >> 6;
  const int l15 = lane & 15, l4 = lane >> 4;
  const int t0 = seg*19, tlen = min(19, 300 - t0);
  const bf16* XG = (const bf16*)(ws + WS_XG);
  bf16* YG = (bf16*)(ws + WS_XG);
  const bf16* wd = (const bf16*)(ws + WS_WD);
  const bf16* gt = (const bf16*)(ws + WS_GT);
  const float* cA = (const float*)(ws + WS_COEFA);
  const float* cB = (const float*)(ws + WS_COEFB);
  const f32x4 z4 = {0.f,0.f,0.f,0.f};

  bf16x8 Wfr[3][2];
  #pragma unroll
  for (int q = 0; q < 3; ++q) {
    const int rt = wv*3 + q, s = rt >> 2, ot1 = rt & 3;
    #pragma unroll
    for (int kk = 0; kk < 2; ++kk)
      Wfr[q][kk] = *(const bf16x8*)&wd[(s*64 + ot1*16 + l15)*64 + kk*32 + 8*l4];
  }
  bf16x8 Gfr[2][3];
  #pragma unroll
  for (int wt = 0; wt < 2; ++wt)
    #pragma unroll
    for (int s = 0; s < 3; ++s)
      Gfr[wt][s] = *(const bf16x8*)&gt[((n*3 + s)*32 + wt*16 + l15)*32 + 8*l4];

  const int o0 = wv*16 + 4*l4;
  float cAr[4], cBr[4];
  #pragma unroll
  for (int r = 0; r < 4; ++r) { cAr[r] = cA[o0 + r]; cBr[r] = cB[o0 + r]; }
  float st[2][4] = {{0.f,0.f,0.f,0.f},{0.f,0.f,0.f,0.f}};
  const int nch = (tlen + 1) >> 1;

  for (int ch = 0; ch < nch; ++ch) {
    // stage1: u[s][o][v] for both t of the chunk
    #pragma unroll
    for (int tt = 0; tt < 2; ++tt) {
      const int t = t0 + ch*2 + tt;
      #pragma unroll
      for (int vt = 0; vt < 2; ++vt) {
        f32x4 acc[3]; acc[0]=z4; acc[1]=z4; acc[2]=z4;
        #pragma unroll
        for (int kk = 0; kk < 2; ++kk) {
          bf16x8 B = *(const bf16x8*)&XG[((size_t)(n*300 + t)*25 + vt*16 + l15)*64 + kk*32 + 8*l4];
          #pragma unroll
          for (int q = 0; q < 3; ++q) acc[q] = mfma16(Wfr[q][kk], B, acc[q]);
        }
        #pragma unroll
        for (int q = 0; q < 3; ++q) {
          const int rt = wv*3 + q, s = rt >> 2, ot1 = rt & 3;
          #pragma unroll
          for (int r = 0; r < 4; ++r)
            UL[(tt*64 + ot1*16 + 4*l4 + r)*104 + s*32 + vt*16 + l15] = (bf16)acc[q][r];
        }
      }
    }
    __syncthreads();
    // stage2: y = sum_sv u*G, + BN/residual/ReLU into registers (reads only)
    float vals[2][2][4];
    #pragma unroll
    for (int tt = 0; tt < 2; ++tt) {
      const int tl = ch*2 + tt;
      f32x4 acc2[2]; acc2[0] = z4; acc2[1] = z4;
      #pragma unroll
      for (int s = 0; s < 3; ++s) {
        bf16x8 Aa = *(const bf16x8*)&UL[(tt*64 + wv*16 + l15)*104 + s*32 + 8*l4];
        acc2[0] = mfma16(Aa, Gfr[0][s], acc2[0]);
        acc2[1] = mfma16(Aa, Gfr[1][s], acc2[1]);
      }
      if (tl < tlen) {
        const int t = t0 + tl;
        #pragma unroll
        for (int wt = 0; wt < 2; ++wt) {
          const int w = wt*16 + l15;
          if (w < 25) {
            bf16x4 rx = *(const bf16x4*)&XG[((size_t)(n*300 + t)*25 + w)*64 + o0];
            #pragma unroll
            for (int r = 0; r < 4; ++r)
              vals[tt][wt][r] = fmaxf(acc2[wt][r]*cAr[r] + cBr[r] + (float)rx[r], 0.f);
          }
        }
      }
    }
    __syncthreads();
    // write y bf16 in-place + accumulate sum-over-t
    #pragma unroll
    for (int tt = 0; tt < 2; ++tt) {
      const int tl = ch*2 + tt;
      if (tl < tlen) {
        const int t = t0 + tl;
        #pragma unroll
        for (int wt = 0; wt < 2; ++wt) {
          const int w = wt*16 + l15;
          if (w < 25) {
            bf16x4 pk;
            #pragma unroll
            for (int r = 0; r < 4; ++r) {
              pk[r] = (bf16)vals[tt][wt][r];
              st[wt][r] += vals[tt][wt][r];
            }
            *(bf16x4*)&YG[((size_t)(n*300 + t)*25 + w)*64 + o0] = pk;
          }
        }
      }
    }
    __syncthreads();
  }
  float* stp = (float*)(ws + WS_STP);
  #pragma unroll
  for (int wt = 0; wt < 2; ++wt) {
    const int w = wt*16 + l15;
    if (w < 25) {
      #pragma unroll
      for (int r = 0; r < 4; ++r)
        stp[((n*16 + seg)*64 + o0 + r)*25 + w] = st[wt][r];
    }
  }
}

// ---------------- k_att: fused se1 + svp(LDS, from bf16 y) + se2 + se3 ----------------
// grid 64 (one block per n), 1024 threads (16 waves).
__global__ __launch_bounds__(1024) void k_att(
    const float* __restrict__ Wsa, const float* __restrict__ bsa,
    const float* __restrict__ Wta, const float* __restrict__ bta,
    const float* __restrict__ Wfc1, const float* __restrict__ bfc1,
    const float* __restrict__ Wfc2, const float* __restrict__ bfc2,
    char* __restrict__ ws) {
  __shared__ float Sm[64][26];
  __shared__ float red0[25][8];
  __shared__ float w1[25];
  __shared__ bf16 Sv[64][304];
  __shared__ float WLa[576];
  __shared__ float redt[304][4];
  __shared__ float w2s[304];
  __shared__ float red2[64][16];
  __shared__ float mS[64];
  __shared__ float hS[32];
  const int n = blockIdx.x, tid = threadIdx.x;
  const float* stp = (const float*)(ws + WS_STP);
  const bf16* YG = (const bf16*)(ws + WS_XG);

  // phase 0: se1 from stp (mean over t via 16 seg partials)
  for (int f = tid; f < 1600; f += 1024) {
    int c = f / 25, v = f % 25;
    float s = 0.f;
    #pragma unroll
    for (int p = 0; p < 16; ++p) s += stp[((n*16 + p)*64 + c)*25 + v];
    Sm[c][v] = s * (1.f/300.f);
  }
  for (int f = tid; f < 576; f += 1024) WLa[f] = Wta[f];
  __syncthreads();
  if (tid < 200) {
    int v = tid >> 3, part = tid & 7;
    float acc = 0.f;
    for (int c = part; c < 64; c += 8) {
      #pragma unroll
      for (int k = 0; k < 25; ++k) {
        int vv = v + k - 12;
        if (vv >= 0 && vv < 25) acc += Wsa[c*25 + k] * Sm[c][vv];
      }
    }
    red0[v][part] = acc;
  }
  __syncthreads();
  if (tid < 25) {
    float a = bsa[0];
    #pragma unroll
    for (int p = 0; p < 8; ++p) a += red0[tid][p];
    float f1 = 1.f + 1.f/(1.f + expf(-a));
    w1[tid] = f1;
    ((float*)(ws + WS_SE1))[n*32 + tid] = f1;
  }
  __syncthreads();
  // phase 1: Sv[c][t] = sum_v y*(1+se1[v])  wave-per-t, lane = c, coalesced 128B rows
  {
    const int wvid = tid >> 6, lane = tid & 63;
    for (int iter = 0; iter < 19; ++iter) {
      int t = iter*16 + wvid;
      if (t < 300) {
        float acc = 0.f;
        #pragma unroll
        for (int v = 0; v < 25; ++v)
          acc += w1[v] * (float)YG[(((size_t)n*300 + t)*25 + v)*64 + lane];
        Sv[lane][t] = (bf16)acc;
      }
    }
  }
  __syncthreads();
  // phase 2: se2 temporal conv (c-split 4 partials x 300 t)
  for (int u = tid; u < 1200; u += 1024) {
    int t = u >> 2, part = u & 3;
    float acc = 0.f;
    for (int c = part*16; c < part*16 + 16; ++c) {
      #pragma unroll
      for (int k = 0; k < 9; ++k) {
        int t2 = t + k - 4;
        if (t2 >= 0 && t2 < 300) acc += WLa[c*9 + k] * (float)Sv[c][t2];
      }
    }
    redt[t][part] = acc;
  }
  __syncthreads();
  if (tid < 300) {
    float a = (redt[tid][0] + redt[tid][1] + redt[tid][2] + redt[tid][3]) * (1.f/25.f) + bta[0];
    float f2 = 1.f + 1.f/(1.f + expf(-a));
    w2s[tid] = f2;
    ((float*)(ws + WS_SE2))[n*304 + tid] = f2;
  }
  __syncthreads();
  // phase 3: se3 squeeze-excite
  {
    int c = tid & 63, part = tid >> 6;
    int tb = part*19, te = min(tb + 19, 300);
    float acc = 0.f;
    for (int t = tb; t < te; ++t) acc += w2s[t] * (float)Sv[c][t];
    red2[c][part] = acc;
  }
  __syncthreads();
  if (tid < 64) {
    float mm = 0.f;
    #pragma unroll
    for (int p = 0; p < 16; ++p) mm += red2[tid][p];
    mS[tid] = mm * (1.f/7500.f);
  }
  __syncthreads();
  if (tid < 32) {
    float a = bfc1[tid];
    for (int c = 0; c < 64; ++c) a += Wfc1[tid*64 + c] * mS[c];
    hS[tid] = fmaxf(a, 0.f);
  }
  __syncthreads();
  if (tid < 64) {
    float a = bfc2[tid];
    #pragma unroll
    for (int j = 0; j < 32; ++j) a += Wfc2[tid*32 + j] * hS[j];
    ((float*)(ws + WS_SE3))[n*64 + tid] = 1.f + 1.f/(1.f + expf(-a));
  }
}

// ---------------- K7: scale + transpose y bf16 [n][t][v][c] -> out f32 [n][c][t][v] ----------------
// grid (19 tc, 64 n), 256 thr. Two 8-t halves through a [200][66] f32 LDS tile.
__global__ __launch_bounds__(256) void k7_scale(
    const char* __restrict__ ws, float* __restrict__ out) {
  __shared__ float tile[200][66];
  __shared__ float w3S[64];
  const int tc = blockIdx.x, n = blockIdx.y, tid = threadIdx.x;
  const bf16* YG = (const bf16*)(ws + WS_XG);
  const float* w1 = (const float*)(ws + WS_SE1) + n*32;
  const float* w2 = (const float*)(ws + WS_SE2) + n*304;
  if (tid < 64) w3S[tid] = ((const float*)(ws + WS_SE3))[n*64 + tid];
  __syncthreads();
  #pragma unroll
  for (int sub = 0; sub < 2; ++sub) {
    const int tb = tc*16 + sub*8;
    const int nT = min(8, 300 - tb);
    if (nT <= 0) break;
    const int rowlen = nT*25;
    // load + scale + transpose into LDS
    for (int u = tid; u < rowlen*8; u += 256) {
      int c8 = u & 7, rest = u >> 3;
      int v = rest % 25, dt = rest / 25;
      int t = tb + dt;
      bf16x8 val = *(const bf16x8*)&YG[(((size_t)n*300 + t)*25 + v)*64 + c8*8];
      float sc = w1[v] * w2[t];
      float* dst = &tile[dt*25 + v][c8*8];
      #pragma unroll
      for (int j = 0; j < 8; ++j) dst[j] = (float)val[j] * sc * w3S[c8*8 + j];
    }
    __syncthreads();
    // coalesced store: per-c rows of rowlen floats
    for (int u = tid; u < 64*rowlen; u += 256) {
      int c = u / rowlen, q = u % rowlen;
      out[(size_t)(n*64 + c)*7500 + tb*25 + q] = tile[q][c];
    }
    __syncthreads();
  }
}

extern "C" void kernel_launch(void* const* d_in, const int* in_sizes, int n_in,
                              void* d_out, int out_size, void* d_ws, size_t ws_size,
                              hipStream_t stream) {
  const float* x    = (const float*)d_in[0];
  const float* A    = (const float*)d_in[1];
  const float* alp  = (const float*)d_in[2];
  const float* Wa   = (const float*)d_in[3];
  const float* ba   = (const float*)d_in[4];
  const float* Wb   = (const float*)d_in[5];
  const float* bb   = (const float*)d_in[6];
  const float* Wd   = (const float*)d_in[7];
  const float* bd   = (const float*)d_in[8];
  const float* gam  = (const float*)d_in[9];
  const float* bet  = (const float*)d_in[10];
  const float* mean = (const float*)d_in[11];
  const float* var  = (const float*)d_in[12];
  const float* Wsa  = (const float*)d_in[13];
  const float* bsa  = (const float*)d_in[14];
  const float* Wta  = (const float*)d_in[15];
  const float* bta  = (const float*)d_in[16];
  const float* Wfc1 = (const float*)d_in[17];
  const float* bfc1 = (const float*)d_in[18];
  const float* Wfc2 = (const float*)d_in[19];
  const float* bfc2 = (const float*)d_in[20];
  char* ws = (char*)d_ws;
  float* out = (float*)d_out;

  k_prep<<<dim3(1), dim3(256), 0, stream>>>(Wa, Wb, Wd, bd, gam, bet, mean, var, ws);
  k_tr<<<dim3(19, 64), dim3(256), 0, stream>>>(x, ws);
  k1_m<<<dim3(16, 64), dim3(256), 0, stream>>>(ba, bb, ws);
  k1b_g<<<dim3(768), dim3(256), 0, stream>>>(A, alp, ws);
  k3_y<<<dim3(16, 64), dim3(256), 0, stream>>>(ws);
  k_att<<<dim3(64), dim3(1024), 0, stream>>>(Wsa, bsa, Wta, bta, Wfc1, bfc1, Wfc2, bfc2, ws);
  k7_scale<<<dim3(19, 64), dim3(256), 0, stream>>>(ws, out);
}